// Round 6
// baseline (55.156 us; speedup 1.0000x reference)
//
#include <hip/hip_runtime.h>

// FeatIterpNFMLP: trilinear grid interp (16^3 x 8ch) + MLP 8->64->64->16 (leaky 0.01)
// Round 6: LDS-staged grid (round 5 core) with two knobs reverted:
//   - __launch_bounds__(512) only: NO min-waves cap -> compiler free on VGPR,
//     no forced spills (round 5's (512,4) forced <=128 VGPR on ~165-VGPR code).
//   - NO XCD swizzle (common element of both failing rounds; natural block
//     round-robin already keeps ~2 examples/XCD resident = 256 KB << 4 MB L2).
// Gathers: 1 ds_read_b128 per corner from a 64 KB bf16 LDS copy of the example
// grid, replacing ~800 divergent L1 transactions per wave (round-2 bottleneck).

typedef __attribute__((ext_vector_type(8)))  short short8;
typedef __attribute__((ext_vector_type(16))) float f32x16;
typedef __attribute__((ext_vector_type(4)))  int   int4v;

static __device__ __forceinline__ unsigned cvt_pk_bf16(float lo, float hi) {
    unsigned r;
    asm("v_cvt_pk_bf16_f32 %0, %1, %2" : "=v"(r) : "v"(lo), "v"(hi));
    return r;
}
// v_permlane32_swap_b32: swaps low-32-lane half of a with high-32-lane half of b.
static __device__ __forceinline__ void permswap(unsigned &a, unsigned &b) {
    asm("v_permlane32_swap_b32 %0, %1" : "+v"(a), "+v"(b));
}
static __device__ __forceinline__ short8 as_s8(int4v v) {
    return __builtin_bit_cast(short8, v);
}

// leaky-relu the 2x2 accum tiles in place, then repack as next-layer B-fragments:
// b[ct][kt], k = kt*16 + 8*half + {0..7}.  acc: col(point)=l31, row(j)=(r&3)+8*(r>>2)+4*half.
static __device__ __forceinline__ void relu_pack(f32x16 acc[2][2], int4v bfr[2][4]) {
    #pragma unroll
    for (int rt = 0; rt < 2; ++rt)
        #pragma unroll
        for (int ct = 0; ct < 2; ++ct)
            #pragma unroll
            for (int r = 0; r < 16; ++r) {
                float a = acc[rt][ct][r];
                acc[rt][ct][r] = fmaxf(a, 0.01f * a);
            }
    #pragma unroll
    for (int ct = 0; ct < 2; ++ct)
        #pragma unroll
        for (int kt = 0; kt < 4; ++kt) {
            const int rs = kt >> 1;
            const int base = (kt & 1) * 8;
            unsigned pa0 = cvt_pk_bf16(acc[rs][ct][base + 0], acc[rs][ct][base + 1]);
            unsigned pa1 = cvt_pk_bf16(acc[rs][ct][base + 2], acc[rs][ct][base + 3]);
            unsigned pb0 = cvt_pk_bf16(acc[rs][ct][base + 4], acc[rs][ct][base + 5]);
            unsigned pb1 = cvt_pk_bf16(acc[rs][ct][base + 6], acc[rs][ct][base + 7]);
            permswap(pa0, pb0);
            permswap(pa1, pb1);
            bfr[ct][kt][0] = (int)pa0;
            bfr[ct][kt][1] = (int)pa1;
            bfr[ct][kt][2] = (int)pb0;
            bfr[ct][kt][3] = (int)pb1;
        }
}

__global__ __launch_bounds__(512) void featmlp_mfma(
    const int* __restrict__ idx,
    const float* __restrict__ x,
    const float* __restrict__ emb,
    const float* __restrict__ W0, const float* __restrict__ b0,
    const float* __restrict__ W1, const float* __restrict__ b1,
    const float* __restrict__ Wout, const float* __restrict__ bout,
    float* __restrict__ out)
{
    __shared__ unsigned short gs[32768];   // 64 KB: one example grid, bf16

    const int tid  = threadIdx.x;
    const int lane = tid & 63;
    const int half = lane >> 5;
    const int l31  = lane & 31;

    const int bid = blockIdx.x;                 // no swizzle
    const int group = bid * 8 + (tid >> 6);     // 8 warps -> 8 consecutive groups
    const long pbase = (long)group * 64;
    const int ex = bid >> 4;                    // 16 blocks per example

    const float* __restrict__ gsrc = emb + ((long)idx[ex] << 15);

    // ---- x loads early (needed right after the barrier) ----
    const long p = pbase + lane;
    const float x0 = x[p * 3 + 0];
    const float x1 = x[p * 3 + 1];
    const float x2 = x[p * 3 + 2];

    // ---- stage example grid f32 -> bf16 LDS, fully coalesced ----
    // 32768 floats / (512 thr * 8 floats) = 8 iters; ds_write_b128 dense.
    for (int i = 0; i < 8; ++i) {
        const int base = i * 4096 + tid * 8;
        const float4 a = *(const float4*)(gsrc + base);
        const float4 b = *(const float4*)(gsrc + base + 4);
        int4v f;
        f[0] = (int)cvt_pk_bf16(a.x, a.y);
        f[1] = (int)cvt_pk_bf16(a.z, a.w);
        f[2] = (int)cvt_pk_bf16(b.x, b.y);
        f[3] = (int)cvt_pk_bf16(b.z, b.w);
        *((int4v*)gs + i * 512 + tid) = f;
    }

    // ---- weight A-fragments (bf16, registers; VALU overlaps staging latency) ----
    // A[row=j][k] = W[k][j]; lane holds row j = rt*32 + l31, k = kt*16 + half*8 + 2m+{0,1}
    int4v w0f[2];
    int4v w1f[2][4];
    int4v wof[4];
    #pragma unroll
    for (int rt = 0; rt < 2; ++rt) {
        const int j = rt * 32 + l31;
        #pragma unroll
        for (int m = 0; m < 4; ++m) {
            const int k0 = (half * 8 + 2 * m) & 7;       // k>=8 lanes: junk, x0 in B
            const int k1 = (half * 8 + 2 * m + 1) & 7;
            w0f[rt][m] = (int)cvt_pk_bf16(W0[k0 * 64 + j], W0[k1 * 64 + j]);
        }
        #pragma unroll
        for (int kt = 0; kt < 4; ++kt)
            #pragma unroll
            for (int m = 0; m < 4; ++m) {
                const int k = kt * 16 + half * 8 + 2 * m;
                w1f[rt][kt][m] = (int)cvt_pk_bf16(W1[k * 64 + j], W1[(k + 1) * 64 + j]);
            }
    }
    {
        const int jo = l31 < 15 ? l31 : 15;              // j>=16 rows unused
        #pragma unroll
        for (int kt = 0; kt < 4; ++kt)
            #pragma unroll
            for (int m = 0; m < 4; ++m) {
                const int k = kt * 16 + half * 8 + 2 * m;
                wof[kt][m] = (int)cvt_pk_bf16(Wout[k * 16 + jo], Wout[(k + 1) * 16 + jo]);
            }
    }

    __syncthreads();   // grid staged

    // ---- trilinear interp from LDS (1 ds_read_b128 per corner) ----
    const float lx = (x0 + 0.5f) * 15.0f;
    const float ly = (x1 + 0.5f) * 15.0f;
    const float lz = (x2 + 0.5f) * 15.0f;
    const float fx = floorf(lx), fy = floorf(ly), fz = floorf(lz);
    const float tx = lx - fx, ty = ly - fy, tz = lz - fz;
    const int ix = (int)fx, iy = (int)fy, iz = (int)fz;

    float feat[8];
    #pragma unroll
    for (int c = 0; c < 8; ++c) feat[c] = 0.0f;
    #pragma unroll
    for (int dz = 0; dz < 2; ++dz)
        #pragma unroll
        for (int dy = 0; dy < 2; ++dy)
            #pragma unroll
            for (int dx = 0; dx < 2; ++dx) {
                const int jx = ix + dx, jy = iy + dy, jz = iz + dz;
                const bool valid = ((unsigned)jx < 16u) & ((unsigned)jy < 16u)
                                 & ((unsigned)jz < 16u);
                float w = (dx ? tx : 1.0f - tx)
                        * (dy ? ty : 1.0f - ty)
                        * (dz ? tz : 1.0f - tz);
                w = valid ? w : 0.0f;
                const int cx = min(max(jx, 0), 15);
                const int cy = min(max(jy, 0), 15);
                const int cz = min(max(jz, 0), 15);
                const int ci = ((cz * 16) + cy) * 16 + cx;       // 16B granules
                const int4v cv = *((const int4v*)gs + ci);
                const unsigned d0 = (unsigned)cv[0];
                const unsigned d1 = (unsigned)cv[1];
                const unsigned d2 = (unsigned)cv[2];
                const unsigned d3 = (unsigned)cv[3];
                feat[0] += w * __uint_as_float(d0 << 16);
                feat[1] += w * __uint_as_float(d0 & 0xFFFF0000u);
                feat[2] += w * __uint_as_float(d1 << 16);
                feat[3] += w * __uint_as_float(d1 & 0xFFFF0000u);
                feat[4] += w * __uint_as_float(d2 << 16);
                feat[5] += w * __uint_as_float(d2 & 0xFFFF0000u);
                feat[6] += w * __uint_as_float(d3 << 16);
                feat[7] += w * __uint_as_float(d3 & 0xFFFF0000u);
            }

    // ---- feat -> B-fragments for layer 0 (K=16, ch 8-15 zero) ----
    int4v bf0[2];
    #pragma unroll
    for (int m = 0; m < 4; ++m) {
        unsigned a = cvt_pk_bf16(feat[2 * m], feat[2 * m + 1]);
        unsigned z = 0u;
        permswap(a, z);
        bf0[0][m] = (int)a;
        bf0[1][m] = (int)z;
    }

    // ---- layer 0 ----
    f32x16 acc0[2][2];
    #pragma unroll
    for (int rt = 0; rt < 2; ++rt) {
        f32x16 bias;
        #pragma unroll
        for (int q = 0; q < 4; ++q) {
            const float4 v = *(const float4*)(b0 + rt * 32 + q * 8 + half * 4);
            bias[4 * q + 0] = v.x; bias[4 * q + 1] = v.y;
            bias[4 * q + 2] = v.z; bias[4 * q + 3] = v.w;
        }
        #pragma unroll
        for (int ct = 0; ct < 2; ++ct)
            acc0[rt][ct] = __builtin_amdgcn_mfma_f32_32x32x16_bf16(
                as_s8(w0f[rt]), as_s8(bf0[ct]), bias, 0, 0, 0);
    }

    int4v b1f[2][4];
    relu_pack(acc0, b1f);

    // ---- layer 1 ----
    f32x16 acc1[2][2];
    #pragma unroll
    for (int rt = 0; rt < 2; ++rt) {
        f32x16 bias;
        #pragma unroll
        for (int q = 0; q < 4; ++q) {
            const float4 v = *(const float4*)(b1 + rt * 32 + q * 8 + half * 4);
            bias[4 * q + 0] = v.x; bias[4 * q + 1] = v.y;
            bias[4 * q + 2] = v.z; bias[4 * q + 3] = v.w;
        }
        #pragma unroll
        for (int ct = 0; ct < 2; ++ct) {
            f32x16 a = bias;
            #pragma unroll
            for (int kt = 0; kt < 4; ++kt)
                a = __builtin_amdgcn_mfma_f32_32x32x16_bf16(
                    as_s8(w1f[rt][kt]), as_s8(b1f[ct][kt]), a, 0, 0, 0);
            acc1[rt][ct] = a;
        }
    }

    int4v b2f[2][4];
    relu_pack(acc1, b2f);

    // ---- layer 2 (rows j<16 valid) ----
    f32x16 bb;
    #pragma unroll
    for (int i = 0; i < 4; ++i) {
        bb[i]      = bout[half * 4 + i];
        bb[4 + i]  = bout[8 + half * 4 + i];
        bb[8 + i]  = 0.0f;
        bb[12 + i] = 0.0f;
    }
    #pragma unroll
    for (int ct = 0; ct < 2; ++ct) {
        f32x16 a = bb;
        #pragma unroll
        for (int kt = 0; kt < 4; ++kt)
            a = __builtin_amdgcn_mfma_f32_32x32x16_bf16(
                as_s8(wof[kt]), as_s8(b2f[ct][kt]), a, 0, 0, 0);
        // j = (r&3) + 8*(r>>2) + 4*half ; point = pbase + ct*32 + l31
        float* o = out + (pbase + ct * 32 + l31) * 16;
        *(float4*)(o + half * 4)     = make_float4(a[0], a[1], a[2], a[3]);
        *(float4*)(o + 8 + half * 4) = make_float4(a[4], a[5], a[6], a[7]);
    }
}

extern "C" void kernel_launch(void* const* d_in, const int* in_sizes, int n_in,
                              void* d_out, int out_size, void* d_ws, size_t ws_size,
                              hipStream_t stream) {
    const int*   idx  = (const int*)  d_in[0];
    const float* x    = (const float*)d_in[1];
    const float* emb  = (const float*)d_in[2];
    const float* W0   = (const float*)d_in[3];
    const float* b0   = (const float*)d_in[4];
    const float* W1   = (const float*)d_in[5];
    const float* b1   = (const float*)d_in[6];
    const float* Wout = (const float*)d_in[7];
    const float* bout = (const float*)d_in[8];
    float* out = (float*)d_out;

    // 8192 groups / 8 per block = 1024 blocks of 512 threads
    featmlp_mfma<<<1024, 512, 0, stream>>>(idx, x, emb, W0, b0, W1, b1,
                                           Wout, bout, out);
}

// Round 8
// 36.604 us; speedup vs baseline: 1.5068x; 1.5068x over previous
//
#include <hip/hip_runtime.h>

// FeatIterpNFMLP: trilinear grid interp (16^3 x 8ch) + MLP 8->64->64->16 (leaky 0.01)
// Round 8: R2 skeleton (known-good: 256-thr blocks, 1 group/wave, global gathers,
// no d_ws, no swizzle, no forced occupancy caps) with ONE change:
//   weight A-fragments live in LDS (14 KB/block), built cooperatively once per
//   block (one warp per fragment family), ds_read_b128 right before each MFMA.
//   -> ~56 fewer persistent VGPRs (target <=~140 => 3-4 waves/SIMD vs R2's ~2)
//   -> weight-setup VALU cost amortized /4.
// Session rule (R4/R5/R7 post-mortems): no d_ws, never force VGPR caps, keep
// pressure far from the spill point (spills + tied-operand cross-lane asm = flaky).

typedef __attribute__((ext_vector_type(8)))  short short8;
typedef __attribute__((ext_vector_type(16))) float f32x16;
typedef __attribute__((ext_vector_type(4)))  int   int4v;

static __device__ __forceinline__ unsigned cvt_pk_bf16(float lo, float hi) {
    unsigned r;
    asm("v_cvt_pk_bf16_f32 %0, %1, %2" : "=v"(r) : "v"(lo), "v"(hi));
    return r;
}
// v_permlane32_swap_b32: swaps low-32-lane half of a with high-32-lane half of b.
static __device__ __forceinline__ void permswap(unsigned &a, unsigned &b) {
    asm("v_permlane32_swap_b32 %0, %1" : "+v"(a), "+v"(b));
}
static __device__ __forceinline__ short8 as_s8(int4v v) {
    return __builtin_bit_cast(short8, v);
}

// leaky-relu the 2x2 accum tiles in place, then repack as next-layer B-fragments:
// b[ct][kt], k = kt*16 + 8*half + {0..7}.  acc: col(point)=l31, row(j)=(r&3)+8*(r>>2)+4*half.
static __device__ __forceinline__ void relu_pack(f32x16 acc[2][2], int4v bfr[2][4]) {
    #pragma unroll
    for (int rt = 0; rt < 2; ++rt)
        #pragma unroll
        for (int ct = 0; ct < 2; ++ct)
            #pragma unroll
            for (int r = 0; r < 16; ++r) {
                float a = acc[rt][ct][r];
                acc[rt][ct][r] = fmaxf(a, 0.01f * a);
            }
    #pragma unroll
    for (int ct = 0; ct < 2; ++ct)
        #pragma unroll
        for (int kt = 0; kt < 4; ++kt) {
            const int rs = kt >> 1;
            const int base = (kt & 1) * 8;
            unsigned pa0 = cvt_pk_bf16(acc[rs][ct][base + 0], acc[rs][ct][base + 1]);
            unsigned pa1 = cvt_pk_bf16(acc[rs][ct][base + 2], acc[rs][ct][base + 3]);
            unsigned pb0 = cvt_pk_bf16(acc[rs][ct][base + 4], acc[rs][ct][base + 5]);
            unsigned pb1 = cvt_pk_bf16(acc[rs][ct][base + 6], acc[rs][ct][base + 7]);
            permswap(pa0, pb0);
            permswap(pa1, pb1);
            bfr[ct][kt][0] = (int)pa0;
            bfr[ct][kt][1] = (int)pa1;
            bfr[ct][kt][2] = (int)pb0;
            bfr[ct][kt][3] = (int)pb1;
        }
}

__global__ __launch_bounds__(256) void featmlp_mfma(
    const int* __restrict__ idx,
    const float* __restrict__ x,
    const float* __restrict__ emb,
    const float* __restrict__ W0, const float* __restrict__ b0,
    const float* __restrict__ W1, const float* __restrict__ b1,
    const float* __restrict__ Wout, const float* __restrict__ bout,
    float* __restrict__ out)
{
    // fid 0-1: w0f[rt]; fid 2-9: w1f[rt][kt] (fid=2+rt*4+kt); fid 10-13: wof[kt]
    __shared__ int4v frag_lds[14 * 64];        // 14 KB

    const int tid  = threadIdx.x;
    const int warp = tid >> 6;
    const int lane = tid & 63;
    const int half = lane >> 5;
    const int l31  = lane & 31;

    const int group = blockIdx.x * 4 + warp;                 // 8192 groups
    const long pbase = (long)group * 64;
    const int  b  = group >> 7;                              // 128 groups / example

    const float* __restrict__ g = emb + ((long)idx[b] << 15);

    // ---- x loads issued first; latency hides under fragment prep ----
    const long p = pbase + lane;
    const float x0 = x[p * 3 + 0];
    const float x1 = x[p * 3 + 1];
    const float x2 = x[p * 3 + 2];

    // ---- cooperative weight-fragment prep (once per block, one warp per family) ----
    // A[row=j][k] = W[k][j]; lane holds row j = rt*32 + l31, k = kt*16 + half*8 + 2m+{0,1}
    if (warp == 0) {                       // w0f: fid 0,1 (K=8 padded; k>=8 junk x0 in B)
        #pragma unroll
        for (int rt = 0; rt < 2; ++rt) {
            const int j = rt * 32 + l31;
            int4v f;
            #pragma unroll
            for (int m = 0; m < 4; ++m) {
                const int k0 = (half * 8 + 2 * m) & 7;
                const int k1 = (half * 8 + 2 * m + 1) & 7;
                f[m] = (int)cvt_pk_bf16(W0[k0 * 64 + j], W0[k1 * 64 + j]);
            }
            frag_lds[rt * 64 + lane] = f;
        }
    } else if (warp == 3) {                // wof: fid 10-13 (rows j>=16 unused, clamp)
        const int jo = l31 < 15 ? l31 : 15;
        #pragma unroll
        for (int kt = 0; kt < 4; ++kt) {
            int4v f;
            #pragma unroll
            for (int m = 0; m < 4; ++m) {
                const int k = kt * 16 + half * 8 + 2 * m;
                f[m] = (int)cvt_pk_bf16(Wout[k * 16 + jo], Wout[(k + 1) * 16 + jo]);
            }
            frag_lds[(10 + kt) * 64 + lane] = f;
        }
    } else {                               // w1f rt = warp-1: fid 2+rt*4+kt
        const int rt = warp - 1;
        const int j = rt * 32 + l31;
        #pragma unroll
        for (int kt = 0; kt < 4; ++kt) {
            int4v f;
            #pragma unroll
            for (int m = 0; m < 4; ++m) {
                const int k = kt * 16 + half * 8 + 2 * m;
                f[m] = (int)cvt_pk_bf16(W1[k * 64 + j], W1[(k + 1) * 64 + j]);
            }
            frag_lds[(2 + rt * 4 + kt) * 64 + lane] = f;
        }
    }

    __syncthreads();   // fragments ready (written once; no later writes)

    // ---- trilinear interp (global gathers, as R2) ----
    const float lx = (x0 + 0.5f) * 15.0f;
    const float ly = (x1 + 0.5f) * 15.0f;
    const float lz = (x2 + 0.5f) * 15.0f;
    const float fx = floorf(lx), fy = floorf(ly), fz = floorf(lz);
    const float tx = lx - fx, ty = ly - fy, tz = lz - fz;
    const int ix = (int)fx, iy = (int)fy, iz = (int)fz;

    float feat[8];
    #pragma unroll
    for (int c = 0; c < 8; ++c) feat[c] = 0.0f;
    #pragma unroll
    for (int dz = 0; dz < 2; ++dz)
        #pragma unroll
        for (int dy = 0; dy < 2; ++dy)
            #pragma unroll
            for (int dx = 0; dx < 2; ++dx) {
                const int jx = ix + dx, jy = iy + dy, jz = iz + dz;
                const bool valid = ((unsigned)jx < 16u) & ((unsigned)jy < 16u)
                                 & ((unsigned)jz < 16u);
                float w = (dx ? tx : 1.0f - tx)
                        * (dy ? ty : 1.0f - ty)
                        * (dz ? tz : 1.0f - tz);
                w = valid ? w : 0.0f;
                const int cx = min(max(jx, 0), 15);
                const int cy = min(max(jy, 0), 15);
                const int cz = min(max(jz, 0), 15);
                const float4* v = (const float4*)(g + ((((cz * 16) + cy) * 16 + cx) * 8));
                const float4 v0 = v[0];
                const float4 v1 = v[1];
                feat[0] += w * v0.x; feat[1] += w * v0.y;
                feat[2] += w * v0.z; feat[3] += w * v0.w;
                feat[4] += w * v1.x; feat[5] += w * v1.y;
                feat[6] += w * v1.z; feat[7] += w * v1.w;
            }

    // ---- feat -> B-fragments for layer 0 (K=16, ch 8-15 zero) ----
    int4v bf0[2];
    #pragma unroll
    for (int m = 0; m < 4; ++m) {
        unsigned a = cvt_pk_bf16(feat[2 * m], feat[2 * m + 1]);
        unsigned z = 0u;
        permswap(a, z);
        bf0[0][m] = (int)a;
        bf0[1][m] = (int)z;
    }

    // ---- layer 0 (w0f from LDS) ----
    f32x16 acc0[2][2];
    #pragma unroll
    for (int rt = 0; rt < 2; ++rt) {
        f32x16 bias;
        #pragma unroll
        for (int q = 0; q < 4; ++q) {
            const float4 v = *(const float4*)(b0 + rt * 32 + q * 8 + half * 4);
            bias[4 * q + 0] = v.x; bias[4 * q + 1] = v.y;
            bias[4 * q + 2] = v.z; bias[4 * q + 3] = v.w;
        }
        const int4v wf = frag_lds[rt * 64 + lane];
        #pragma unroll
        for (int ct = 0; ct < 2; ++ct)
            acc0[rt][ct] = __builtin_amdgcn_mfma_f32_32x32x16_bf16(
                as_s8(wf), as_s8(bf0[ct]), bias, 0, 0, 0);
    }

    int4v b1f[2][4];
    relu_pack(acc0, b1f);

    // ---- layer 1 (w1f from LDS) ----
    f32x16 acc1[2][2];
    #pragma unroll
    for (int rt = 0; rt < 2; ++rt) {
        f32x16 bias;
        #pragma unroll
        for (int q = 0; q < 4; ++q) {
            const float4 v = *(const float4*)(b1 + rt * 32 + q * 8 + half * 4);
            bias[4 * q + 0] = v.x; bias[4 * q + 1] = v.y;
            bias[4 * q + 2] = v.z; bias[4 * q + 3] = v.w;
        }
        #pragma unroll
        for (int ct = 0; ct < 2; ++ct) {
            f32x16 a = bias;
            #pragma unroll
            for (int kt = 0; kt < 4; ++kt) {
                const int4v wf = frag_lds[(2 + rt * 4 + kt) * 64 + lane];
                a = __builtin_amdgcn_mfma_f32_32x32x16_bf16(
                    as_s8(wf), as_s8(b1f[ct][kt]), a, 0, 0, 0);
            }
            acc1[rt][ct] = a;
        }
    }

    int4v b2f[2][4];
    relu_pack(acc1, b2f);

    // ---- layer 2 (wof from LDS; rows j<16 valid) ----
    f32x16 bb;
    #pragma unroll
    for (int i = 0; i < 4; ++i) {
        bb[i]      = bout[half * 4 + i];
        bb[4 + i]  = bout[8 + half * 4 + i];
        bb[8 + i]  = 0.0f;
        bb[12 + i] = 0.0f;
    }
    #pragma unroll
    for (int ct = 0; ct < 2; ++ct) {
        f32x16 a = bb;
        #pragma unroll
        for (int kt = 0; kt < 4; ++kt) {
            const int4v wf = frag_lds[(10 + kt) * 64 + lane];
            a = __builtin_amdgcn_mfma_f32_32x32x16_bf16(
                as_s8(wf), as_s8(b2f[ct][kt]), a, 0, 0, 0);
        }
        // j = (r&3) + 8*(r>>2) + 4*half ; point = pbase + ct*32 + l31
        float* o = out + (pbase + ct * 32 + l31) * 16;
        *(float4*)(o + half * 4)     = make_float4(a[0], a[1], a[2], a[3]);
        *(float4*)(o + 8 + half * 4) = make_float4(a[4], a[5], a[6], a[7]);
    }
}

extern "C" void kernel_launch(void* const* d_in, const int* in_sizes, int n_in,
                              void* d_out, int out_size, void* d_ws, size_t ws_size,
                              hipStream_t stream) {
    const int*   idx  = (const int*)  d_in[0];
    const float* x    = (const float*)d_in[1];
    const float* emb  = (const float*)d_in[2];
    const float* W0   = (const float*)d_in[3];
    const float* b0   = (const float*)d_in[4];
    const float* W1   = (const float*)d_in[5];
    const float* b1   = (const float*)d_in[6];
    const float* Wout = (const float*)d_in[7];
    const float* bout = (const float*)d_in[8];
    float* out = (float*)d_out;

    // 8192 groups / 4 per block = 2048 blocks of 256 threads
    featmlp_mfma<<<2048, 256, 0, stream>>>(idx, x, emb, W0, b0, W1, b1,
                                           Wout, bout, out);
}